// Round 9
// baseline (246.709 us; speedup 1.0000x reference)
//
#include <hip/hip_runtime.h>
#include <math.h>

#define BATCH 131072
#define DIM 256
#define NK 5
#define BT 3.0f
#define NBLK 1024    // 4 blocks/CU x 256 CU, exactly co-resident
#define NTHR 512     // 8 waves/block -> 32 waves/CU
#define ITERS 8      // BATCH / (NBLK * 8 waves * 2 rows)

__global__ __launch_bounds__(NTHR, 8) void rqs_kernel(
    const float* __restrict__ u,
    const float* __restrict__ wp,
    const float* __restrict__ hp,
    const float* __restrict__ dp,
    float* __restrict__ x_out,
    float* __restrict__ ld_out)
{
    // r7 base (93.5 us/dispatch, FETCH 65.7 MB, conflicts 786K) + ONE change:
    // cross-iteration register prefetch of u (T14 issue-early/consume-late).
    // Evidence: the only clean adjacent-pair A/B of the session (r1 vs r2,
    // identical kernel +/- prefetch, same epoch) = 127 vs 145 us (+14%), FETCH
    // 247 vs 292 MB. r6's traffic blowup was the remap/permute + vector-nt-store
    // bundle, not the prefetch.
    //
    // Table: split per-(bin,dim) records, 16 B/lane gather stride (conflict-free
    // ds_read_b128; interleaved 32 B stride cost 6.36M conflict cycles, r0).
    //   tabA[k*DIM+dim] = (xk, 1/width, s = dk+dk1-2*delta, delta)
    //   tabB[k*DIM+dim] = (p = h*(delta-dk), q = h*dk, yk, rb = 2*(delta-dk))
    // Math:  theta = (uc-xk)*iw
    //        denom = fma(fma(-s,th,s),th,delta)            (= delta + s*th*(1-th))
    //        num   = th*fma(p,th,q)                        (= h*(delta*th^2 + dk*th(1-th)))
    //        ldq   = fma(fma(s,th,rb),th,dk)               (= dk1*th^2+2delta*th(1-th)+dk*(1-th)^2)
    //        ld    = log(ldq * delta^2 * invd^2)
    // At th==0 (low tail, dk=1) and th==1 (high tail, dk1=1) the log argument is 1
    // -> ld == 0, so no 'inside' select needed on ld.
    __shared__ float4 tabA[NK * DIM];   // 20480 B
    __shared__ float4 tabB[NK * DIM];   // 20480 B ; total 40960 -> 4 blocks = 160 KiB/CU
    const int tid = threadIdx.x;

    if (tid < DIM) {
        const int dm = tid;
        float v[NK], wid[NK], xpos[NK], hei[NK], ypos[NK], dv[NK + 1];
        float mx, sum, scale, c;

        mx = -1e30f;
        #pragma unroll
        for (int k = 0; k < NK; k++) { v[k] = wp[dm * NK + k]; mx = fmaxf(mx, v[k]); }
        sum = 0.f;
        #pragma unroll
        for (int k = 0; k < NK; k++) { v[k] = expf(v[k] - mx); sum += v[k]; }
        scale = 6.0f / sum;
        c = -BT;
        #pragma unroll
        for (int k = 0; k < NK; k++) { wid[k] = v[k] * scale; xpos[k] = c; c += wid[k]; }

        mx = -1e30f;
        #pragma unroll
        for (int k = 0; k < NK; k++) { v[k] = hp[dm * NK + k]; mx = fmaxf(mx, v[k]); }
        sum = 0.f;
        #pragma unroll
        for (int k = 0; k < NK; k++) { v[k] = expf(v[k] - mx); sum += v[k]; }
        scale = 6.0f / sum;
        c = -BT;
        #pragma unroll
        for (int k = 0; k < NK; k++) { hei[k] = v[k] * scale; ypos[k] = c; c += hei[k]; }

        dv[0] = 1.0f; dv[NK] = 1.0f;
        #pragma unroll
        for (int k = 0; k < 4; k++) dv[1 + k] = log1pf(expf(dp[dm * 4 + k]));

        #pragma unroll
        for (int k = 0; k < NK; k++) {
            float iw  = 1.0f / wid[k];
            float dlt = hei[k] * iw;
            float dk  = dv[k], dk1 = dv[k + 1];
            tabA[k * DIM + dm] = make_float4(xpos[k], iw, dk + dk1 - 2.0f * dlt, dlt);
            tabB[k * DIM + dm] = make_float4(hei[k] * (dlt - dk), hei[k] * dk,
                                             ypos[k], 2.0f * (dlt - dk));
        }
    }
    __syncthreads();

    const int lane = tid & 63;
    const int wv   = tid >> 6;

    // thread owns dims lane, lane+64, lane+128, lane+192; preload interior x-knots
    float kn[4][4];
    #pragma unroll
    for (int j = 0; j < 4; j++)
        #pragma unroll
        for (int i = 0; i < 4; i++)
            kn[j][i] = tabA[(i + 1) * DIM + lane + 64 * j].x;

    const int g = (blockIdx.x << 3) | wv;   // global wave id, 0..8191

    // prefetch iteration 0's u values
    float uin[2][4];
    {
        const float* up = u + ((size_t)(g << 1)) * DIM + lane;
        #pragma unroll
        for (int rr = 0; rr < 2; rr++)
            #pragma unroll
            for (int j = 0; j < 4; j++)
                uin[rr][j] = up[rr * DIM + 64 * j];
    }

    for (int it = 0; it < ITERS; it++) {
        const int r0 = (it << 14) | (g << 1);   // 16384 contiguous rows per sweep

        // issue NEXT iteration's u loads before this iteration's compute:
        // ~600 cy of HBM latency hides under the ~600 cy of math below.
        float unx[2][4];
        if (it + 1 < ITERS) {
            const float* up = u + ((size_t)(r0 + 16384)) * DIM + lane;
            #pragma unroll
            for (int rr = 0; rr < 2; rr++)
                #pragma unroll
                for (int j = 0; j < 4; j++)
                    unx[rr][j] = up[rr * DIM + 64 * j];
        }

        float lds[2] = {0.f, 0.f};
        #pragma unroll
        for (int rr = 0; rr < 2; rr++) {
            float xo[4];
            #pragma unroll
            for (int j = 0; j < 4; j++) {
                float uval = uin[rr][j];
                float uc = fminf(fmaxf(uval, -BT), BT);
                int idx = 0;
                idx += (uc >= kn[j][0]);
                idx += (uc >= kn[j][1]);
                idx += (uc >= kn[j][2]);
                idx += (uc >= kn[j][3]);
                const int off = idx * DIM + lane + 64 * j;
                float4 A  = tabA[off];
                float4 Bv = tabB[off];
                float xk = A.x, iw = A.y, s = A.z, dlt = A.w;
                float p = Bv.x, q = Bv.y, yk = Bv.z, rb = Bv.w;

                float th    = (uc - xk) * iw;
                float dk    = fmaf(-0.5f, rb, dlt);
                float r2    = dlt * dlt;
                float denom = fmaf(fmaf(-s, th, s), th, dlt);
                float invd  = __builtin_amdgcn_rcpf(denom);
                float num   = th * fmaf(p, th, q);
                float x_in  = fmaf(num, invd, yk);
                float ldq   = fmaf(fmaf(s, th, rb), th, dk);
                float ld    = __logf(ldq * r2 * invd * invd);

                xo[j] = (uc == uval) ? x_in : uval;
                lds[rr] += ld;           // == 0 (to fp eps) for tail elements
            }
            float* xp = x_out + (size_t)(r0 + rr) * DIM + lane;
            #pragma unroll
            for (int j = 0; j < 4; j++)
                __builtin_nontemporal_store(xo[j], xp + 64 * j);
        }

        #pragma unroll
        for (int off = 32; off > 0; off >>= 1) {
            lds[0] += __shfl_down(lds[0], off, 64);
            lds[1] += __shfl_down(lds[1], off, 64);
        }
        if (lane == 0) {
            __builtin_nontemporal_store(lds[0], ld_out + r0);
            __builtin_nontemporal_store(lds[1], ld_out + r0 + 1);
        }

        if (it + 1 < ITERS) {
            #pragma unroll
            for (int rr = 0; rr < 2; rr++)
                #pragma unroll
                for (int j = 0; j < 4; j++)
                    uin[rr][j] = unx[rr][j];
        }
    }
}

extern "C" void kernel_launch(void* const* d_in, const int* in_sizes, int n_in,
                              void* d_out, int out_size, void* d_ws, size_t ws_size,
                              hipStream_t stream) {
    const float* u  = (const float*)d_in[0];
    const float* w  = (const float*)d_in[1];
    const float* h  = (const float*)d_in[2];
    const float* dd = (const float*)d_in[3];
    float* x  = (float*)d_out;
    float* ld = x + (size_t)BATCH * DIM;
    rqs_kernel<<<NBLK, NTHR, 0, stream>>>(u, w, h, dd, x, ld);
}

// Round 10
// 245.119 us; speedup vs baseline: 1.0065x; 1.0065x over previous
//
#include <hip/hip_runtime.h>
#include <math.h>

#define BATCH 131072
#define DIM 256
#define NK 5
#define BT 3.0f
#define NBLK 1024    // 4 blocks/CU x 256 CU, exactly co-resident
#define NTHR 512     // 8 waves/block -> 32 waves/CU
#define ITERS 8      // BATCH / (NBLK * 8 waves * 2 rows)

__global__ __launch_bounds__(NTHR, 8) void rqs_kernel(
    const float* __restrict__ u,
    const float* __restrict__ wp,
    const float* __restrict__ hp,
    const float* __restrict__ dp,
    float* __restrict__ x_out,
    float* __restrict__ ld_out)
{
    // r9 base (90 us/dispatch, FETCH ~72 MB, conflicts 786K) + ONE change:
    // the 8 elements per iteration are explicitly software-pipelined, depth 2:
    //   region e: { math(e) ; bin-search(e+2) ; issue 2x ds_read_b128(e+2) } ; sched_barrier(0)
    // so element e+2's LDS gather latency (~120 cy) hides under element e+1's
    // math (~100 cy). r9's counter evidence (VGPR stuck at 32) showed the
    // scheduler SINKS source-level reordering; sched_barrier(0) between regions
    // pins the issue order. Rotation arrays use only compile-time indices.
    //
    // Table: split per-(bin,dim) records, 16 B/lane gather stride (conflict-free
    // ds_read_b128; interleaved 32 B stride cost 6.36M conflict cycles, r0).
    //   tabA[k*DIM+dim] = (xk, 1/width, s = dk+dk1-2*delta, delta)
    //   tabB[k*DIM+dim] = (p = h*(delta-dk), q = h*dk, yk, rb = 2*(delta-dk))
    // tabB sits at tabA+20480 B: one LDS address register per element, the
    // second read uses the 16-bit ds offset immediate.
    // Math:  theta = (uc-xk)*iw
    //        denom = fma(fma(-s,th,s),th,delta)
    //        num   = th*fma(p,th,q)
    //        ldq   = fma(fma(s,th,rb),th,dk)
    //        ld    = log(ldq * delta^2 * invd^2)   (== 0 in the identity tails)
    __shared__ float4 tabA[NK * DIM];   // 20480 B
    __shared__ float4 tabB[NK * DIM];   // 20480 B ; total 40960 -> 4 blocks = 160 KiB/CU
    const int tid = threadIdx.x;

    if (tid < DIM) {
        const int dm = tid;
        float v[NK], wid[NK], xpos[NK], hei[NK], ypos[NK], dv[NK + 1];
        float mx, sum, scale, c;

        mx = -1e30f;
        #pragma unroll
        for (int k = 0; k < NK; k++) { v[k] = wp[dm * NK + k]; mx = fmaxf(mx, v[k]); }
        sum = 0.f;
        #pragma unroll
        for (int k = 0; k < NK; k++) { v[k] = expf(v[k] - mx); sum += v[k]; }
        scale = 6.0f / sum;
        c = -BT;
        #pragma unroll
        for (int k = 0; k < NK; k++) { wid[k] = v[k] * scale; xpos[k] = c; c += wid[k]; }

        mx = -1e30f;
        #pragma unroll
        for (int k = 0; k < NK; k++) { v[k] = hp[dm * NK + k]; mx = fmaxf(mx, v[k]); }
        sum = 0.f;
        #pragma unroll
        for (int k = 0; k < NK; k++) { v[k] = expf(v[k] - mx); sum += v[k]; }
        scale = 6.0f / sum;
        c = -BT;
        #pragma unroll
        for (int k = 0; k < NK; k++) { hei[k] = v[k] * scale; ypos[k] = c; c += hei[k]; }

        dv[0] = 1.0f; dv[NK] = 1.0f;
        #pragma unroll
        for (int k = 0; k < 4; k++) dv[1 + k] = log1pf(expf(dp[dm * 4 + k]));

        #pragma unroll
        for (int k = 0; k < NK; k++) {
            float iw  = 1.0f / wid[k];
            float dlt = hei[k] * iw;
            float dk  = dv[k], dk1 = dv[k + 1];
            tabA[k * DIM + dm] = make_float4(xpos[k], iw, dk + dk1 - 2.0f * dlt, dlt);
            tabB[k * DIM + dm] = make_float4(hei[k] * (dlt - dk), hei[k] * dk,
                                             ypos[k], 2.0f * (dlt - dk));
        }
    }
    __syncthreads();

    const int lane = tid & 63;
    const int wv   = tid >> 6;

    // thread owns dims lane, lane+64, lane+128, lane+192; preload interior x-knots
    float kn[4][4];
    #pragma unroll
    for (int j = 0; j < 4; j++)
        #pragma unroll
        for (int i = 0; i < 4; i++)
            kn[j][i] = tabA[(i + 1) * DIM + lane + 64 * j].x;

    const int g = (blockIdx.x << 3) | wv;   // global wave id, 0..8191

// pipeline stage macros — (e) must be a literal so all indices are compile-time
#define PIPE_ISSUE(e) do {                                                     \
        const int rr_ = (e) >> 2, j_ = (e) & 3, s_ = (e) & 1;                  \
        float uval_ = uin[rr_][j_];                                            \
        float c_ = fminf(fmaxf(uval_, -BT), BT);                               \
        int idx_ = (int)(c_ >= kn[j_][0]) + (int)(c_ >= kn[j_][1])             \
                 + (int)(c_ >= kn[j_][2]) + (int)(c_ >= kn[j_][3]);            \
        const int off_ = (idx_ << 8) + lane + (j_ << 6);                       \
        As[s_] = tabA[off_];                                                   \
        Bs[s_] = tabB[off_];                                                   \
        ucs[s_] = c_; uvs[s_] = uval_;                                         \
    } while (0)

#define PIPE_MATH(e) do {                                                      \
        const int rr_ = (e) >> 2, j_ = (e) & 3, s_ = (e) & 1;                  \
        float4 A = As[s_]; float4 Bv = Bs[s_];                                 \
        float c_ = ucs[s_], uval_ = uvs[s_];                                   \
        float xk = A.x, iw = A.y, ss_ = A.z, dlt = A.w;                        \
        float p = Bv.x, q = Bv.y, yk = Bv.z, rb = Bv.w;                        \
        float th    = (c_ - xk) * iw;                                          \
        float dk    = fmaf(-0.5f, rb, dlt);                                    \
        float r2    = dlt * dlt;                                               \
        float denom = fmaf(fmaf(-ss_, th, ss_), th, dlt);                      \
        float invd  = __builtin_amdgcn_rcpf(denom);                            \
        float num   = th * fmaf(p, th, q);                                     \
        float x_in  = fmaf(num, invd, yk);                                     \
        float ldq   = fmaf(fmaf(ss_, th, rb), th, dk);                         \
        float ld_   = __logf(ldq * r2 * invd * invd);                          \
        float xo_ = (c_ == uval_) ? x_in : uval_;                              \
        __builtin_nontemporal_store(                                           \
            xo_, x_out + (size_t)(r0 + rr_) * DIM + lane + (j_ << 6));         \
        if ((e) < 4) acc0 += ld_; else acc1 += ld_;                            \
    } while (0)

    for (int it = 0; it < ITERS; it++) {
        const int r0 = (it << 14) | (g << 1);   // 16384 contiguous rows per sweep
        const float* up = u + (size_t)r0 * DIM + lane;

        float uin[2][4];
        #pragma unroll
        for (int rr = 0; rr < 2; rr++)
            #pragma unroll
            for (int j = 0; j < 4; j++)
                uin[rr][j] = up[rr * DIM + 64 * j];

        float4 As[2], Bs[2];
        float ucs[2], uvs[2];
        float acc0 = 0.f, acc1 = 0.f;

        // prologue: fill the 2-deep gather pipeline
        PIPE_ISSUE(0);
        PIPE_ISSUE(1);
        __builtin_amdgcn_sched_barrier(0);
        // steady state: math(e) overlaps the in-flight gathers of e+1, e+2
        PIPE_MATH(0); PIPE_ISSUE(2); __builtin_amdgcn_sched_barrier(0);
        PIPE_MATH(1); PIPE_ISSUE(3); __builtin_amdgcn_sched_barrier(0);
        PIPE_MATH(2); PIPE_ISSUE(4); __builtin_amdgcn_sched_barrier(0);
        PIPE_MATH(3); PIPE_ISSUE(5); __builtin_amdgcn_sched_barrier(0);
        PIPE_MATH(4); PIPE_ISSUE(6); __builtin_amdgcn_sched_barrier(0);
        PIPE_MATH(5); PIPE_ISSUE(7); __builtin_amdgcn_sched_barrier(0);
        PIPE_MATH(6);
        PIPE_MATH(7);

        #pragma unroll
        for (int off = 32; off > 0; off >>= 1) {
            acc0 += __shfl_down(acc0, off, 64);
            acc1 += __shfl_down(acc1, off, 64);
        }
        if (lane == 0) {
            __builtin_nontemporal_store(acc0, ld_out + r0);
            __builtin_nontemporal_store(acc1, ld_out + r0 + 1);
        }
    }

#undef PIPE_ISSUE
#undef PIPE_MATH
}

extern "C" void kernel_launch(void* const* d_in, const int* in_sizes, int n_in,
                              void* d_out, int out_size, void* d_ws, size_t ws_size,
                              hipStream_t stream) {
    const float* u  = (const float*)d_in[0];
    const float* w  = (const float*)d_in[1];
    const float* h  = (const float*)d_in[2];
    const float* dd = (const float*)d_in[3];
    float* x  = (float*)d_out;
    float* ld = x + (size_t)BATCH * DIM;
    rqs_kernel<<<NBLK, NTHR, 0, stream>>>(u, w, h, dd, x, ld);
}